// Round 12
// baseline (272.715 us; speedup 1.0000x reference)
//
#include <hip/hip_runtime.h>
#include <hip/hip_bf16.h>

// GCN 2-layer, N=100000, E=1.6M, 64->64(relu)->32.
// out[d] = dis[d]*(sum_{s in N(d)} dis[s]*h[s] + dis[d]*h[d]) + b  (per layer).
// Pipeline (4 kernels + memset), NO pedge, NO global degree atomics:
//  pass1+gemm1: partition edges into 1563 dst-range buckets (64 dsts each,
//    rec = (src<<6)|(dst&63)); x@W1 -> h1u bf16 (single rounding).
//  degree_kernel: one block per bucket re-scans rec, LDS-histograms the
//    6-bit dst, writes dis[] = rsqrt(deg+1).
//  agg1_gemm2_half: one 256-thr block per HALF bucket (32 dsts) -- r2's
//    proven fused geometry with self-binning. LDS 25.3 KB (lists 8K + z 8.7K
//    + W2 8K) -> 6 blocks/CU, avoiding r8's 42.5KB occupancy cliff.
//    Bins its half, 8 lanes/node weighted gathers (w = dis[s]), z f32 in
//    LDS, 32x32 gemm tile @ W2 -> h2s bf16 pre-scaled by dis[row].
//  agg2_fb: self-binned, 4 lanes/node x 64, dn local, writes out f32.
// Locked-in lessons: r7 no per-edge LDS f32 atomics; r8 no big-LDS gather
// blocks; r9 no scattered global atomics; r3-r6 gather FETCH ~85-97MB is
// compulsory (each XCD pulls the table through its L2) at ~2.3TB/s.

constexpr int N = 100000;
constexpr int E = 1600000;
constexpr int NBINS = 1563;    // ceil(N/64) dst-ranges of 64
constexpr int HB    = 1568;    // padded bin count for pass1 LDS scratch
constexpr int CAP   = 1536;    // records per range (mean 1023, +16 sigma)
constexpr int P1B   = 391;     // pass1 blocks (4096 edges each)
constexpr int GB    = 1563;    // gemm1 blocks (64 rows each)

// ---- fused: pass1 partition (bid<P1B) | gemm1 outer-product (else) ----
__global__ void __launch_bounds__(256) fused_pass1_gemm1(
    const float* __restrict__ x, const float* __restrict__ W1,
    __hip_bfloat16* __restrict__ h1u,
    const int* __restrict__ src, const int* __restrict__ dst,
    int* __restrict__ cursor, unsigned* __restrict__ rec) {
    __shared__ float ws[64][64];    // 16 KB (pass1 reuses ws+xsT as scratch)
    __shared__ float xsT[64][64];   // 16 KB
    const int bid = blockIdx.x;
    const int t = threadIdx.x;
    if (bid < P1B) {
        int* hist  = (int*)ws;          // HB ints (spills into xsT: both
        int* rbase = hist + HB;         // arrays unused by pass1 blocks)
        int* rcur  = rbase + HB;
        for (int i = t; i < HB; i += 256) hist[i] = 0;
        __syncthreads();
        int myd[16], mys[16];
        const int e0 = bid * 4096;
#pragma unroll
        for (int it = 0; it < 16; ++it) {
            int idx = e0 + it * 256 + t;
            bool ok = idx < E;
            myd[it] = ok ? dst[idx] : -1;
            mys[it] = ok ? src[idx] : 0;
            if (ok) atomicAdd(&hist[myd[it] >> 6], 1);
        }
        __syncthreads();
        for (int i = t; i < HB; i += 256) {
            int h = hist[i];
            rbase[i] = (h > 0) ? atomicAdd(&cursor[i], h) : 0;
            rcur[i] = 0;
        }
        __syncthreads();
#pragma unroll
        for (int it = 0; it < 16; ++it) {
            if (myd[it] >= 0) {
                int cb = myd[it] >> 6;
                int r = atomicAdd(&rcur[cb], 1);
                int pos = rbase[cb] + r;
                if (pos < CAP)
                    rec[(size_t)cb * CAP + pos] =
                        ((unsigned)mys[it] << 6) | ((unsigned)myd[it] & 63u);
            }
        }
    } else {
        // ---- gemm block: 64 rows, outer-product 4x4 per thread ----
        const int row0 = (bid - P1B) * 64;
        for (int i = t * 4; i < 64 * 64; i += 1024) {
            float4 v = *(const float4*)(W1 + i);
            ws[i >> 6][i & 63]       = v.x;
            ws[i >> 6][(i & 63) + 1] = v.y;
            ws[i >> 6][(i & 63) + 2] = v.z;
            ws[i >> 6][(i & 63) + 3] = v.w;
        }
        {
            const int r  = t & 63;
            const int k0 = (t >> 6) * 16;
            const int gr = row0 + r;
            if (gr < N) {
#pragma unroll
                for (int kk = 0; kk < 16; kk += 4) {
                    float4 v = *(const float4*)(x + (size_t)gr * 64 + k0 + kk);
                    xsT[k0 + kk][r]     = v.x;
                    xsT[k0 + kk + 1][r] = v.y;
                    xsT[k0 + kk + 2][r] = v.z;
                    xsT[k0 + kk + 3][r] = v.w;
                }
            } else {
#pragma unroll
                for (int kk = 0; kk < 16; ++kk) xsT[k0 + kk][r] = 0.0f;
            }
        }
        __syncthreads();
        const int c4 = (t & 15) * 4;
        const int r4 = (t >> 4) * 4;
        float acc[4][4];
#pragma unroll
        for (int i = 0; i < 4; ++i)
#pragma unroll
            for (int j = 0; j < 4; ++j) acc[i][j] = 0.0f;
#pragma unroll 4
        for (int k = 0; k < 64; ++k) {
            float4 wv = *(const float4*)&ws[k][c4];
            float4 xv = *(const float4*)&xsT[k][r4];
            float xa[4] = {xv.x, xv.y, xv.z, xv.w};
            float wa[4] = {wv.x, wv.y, wv.z, wv.w};
#pragma unroll
            for (int i = 0; i < 4; ++i)
#pragma unroll
                for (int j = 0; j < 4; ++j) acc[i][j] += xa[i] * wa[j];
        }
#pragma unroll
        for (int i = 0; i < 4; ++i) {
            const int gr = row0 + r4 + i;
            if (gr < N) {
                unsigned short o[4];
#pragma unroll
                for (int j = 0; j < 4; ++j)
                    o[j] = __bfloat16_as_ushort(__float2bfloat16(acc[i][j]));
                *(ushort4*)((unsigned short*)h1u + (size_t)gr * 64 + c4) =
                    *(const ushort4*)o;
            }
        }
    }
}

// ---- degree: one block per bucket; histogram 6-bit dst -> dis[] ----
__global__ void __launch_bounds__(256) degree_kernel(
    const unsigned* __restrict__ rec, const int* __restrict__ cursor,
    float* __restrict__ dis) {
    __shared__ int cur[64];
    const int t = threadIdx.x;
    const int cb = blockIdx.x;
    if (t < 64) cur[t] = 0;
    __syncthreads();
    int m = cursor[cb];
    if (m > CAP) m = CAP;
    const unsigned* rb_ = rec + (size_t)cb * CAP;
    for (int i = t; i < m; i += 256)
        atomicAdd(&cur[rb_[i] & 63u], 1);
    __syncthreads();
    if (t < 64) {
        const int n = cb * 64 + t;
        if (n < N) dis[n] = rsqrtf((float)cur[t] + 1.0f);
    }
}

__device__ __forceinline__ void bf8_fma(float* acc, uint4 r, float w) {
    const unsigned u[4] = {r.x, r.y, r.z, r.w};
#pragma unroll
    for (int k = 0; k < 4; ++k) {
        acc[2 * k]     += __uint_as_float(u[k] << 16) * w;
        acc[2 * k + 1] += __uint_as_float(u[k] & 0xffff0000u) * w;
    }
}

__device__ __forceinline__ void bf8_acc(float* acc, uint4 r) {
    const unsigned u[4] = {r.x, r.y, r.z, r.w};
#pragma unroll
    for (int k = 0; k < 4; ++k) {
        acc[2 * k]     += __uint_as_float(u[k] << 16);
        acc[2 * k + 1] += __uint_as_float(u[k] & 0xffff0000u);
    }
}

// ---- fused layer-1 agg + gemm2, HALF-bucket blocks (r2 geometry).
// Block (cb = bid>>1, half = bid&1): bins the 32 dsts of its half from the
// 64-dst rec bucket; 8 lanes/node weighted gathers (w = dis[s]); z f32 in
// LDS (stride 68); 32x32 gemm tile @ W2 -> h2s bf16 pre-scaled by dis. ----
__global__ void __launch_bounds__(256) agg1_gemm2_half(
    const __hip_bfloat16* __restrict__ h1u, const unsigned* __restrict__ rec,
    const int* __restrict__ cursor, const float* __restrict__ dis,
    const float* __restrict__ b, const float* __restrict__ W2,
    __hip_bfloat16* __restrict__ h2s) {
    __shared__ float    ws[64][32];      // 8 KB   W2
    __shared__ float    zs[32 * 68];     // 8.7 KB z rows, bank-spread
    __shared__ unsigned lists[32 * 64];  // 8 KB   per-node src lists
    __shared__ int      cur[32];
    __shared__ float    dis_l[32];
    const int t = threadIdx.x;
    const int cb = blockIdx.x >> 1;
    const int half = blockIdx.x & 1;
    for (int i = t; i < 64 * 32; i += 256) ws[i >> 5][i & 31] = W2[i];
    if (t < 32) cur[t] = 0;
    __syncthreads();

    // Phase A: bin this half's records
    int m = cursor[cb];
    if (m > CAP) m = CAP;
    const unsigned* rb_ = rec + (size_t)cb * CAP;
    const int hbase = half * 32;
    for (int i = t; i < m; i += 256) {
        unsigned u = rb_[i];
        int dl = (int)(u & 63u) - hbase;
        if ((unsigned)dl < 32u) {
            int r = atomicAdd(&cur[dl], 1);
            if (r < 64) lists[dl * 64 + r] = u >> 6;
        }
    }
    __syncthreads();

    // Phase B: gather (32 nodes x 8 lanes)
    const unsigned short* hp = (const unsigned short*)h1u;
    const int nl = t >> 3;
    const int n = cb * 64 + hbase + nl;
    const int fq = (t & 7) * 8;
    const int c = cur[nl];
    const int deg = (c < 64) ? c : 64;
    const unsigned* lp = &lists[nl * 64];
    float acc[8];
#pragma unroll
    for (int i = 0; i < 8; ++i) acc[i] = 0.0f;
    int j = 0;
    for (; j + 2 <= deg; j += 2) {
        unsigned s0 = lp[j], s1 = lp[j + 1];
        float w0 = dis[s0], w1 = dis[s1];
        uint4 r0 = *(const uint4*)(hp + (size_t)s0 * 64 + fq);
        uint4 r1 = *(const uint4*)(hp + (size_t)s1 * 64 + fq);
        bf8_fma(acc, r0, w0);
        bf8_fma(acc, r1, w1);
    }
    if (j < deg) {
        unsigned s0 = lp[j];
        float w0 = dis[s0];
        uint4 r0 = *(const uint4*)(hp + (size_t)s0 * 64 + fq);
        bf8_fma(acc, r0, w0);
    }
    float* zr = &zs[nl * 68 + fq];
    if (n < N) {
        const float dn = rsqrtf((float)c + 1.0f);
        uint4 sr = *(const uint4*)(hp + (size_t)n * 64 + fq);
        bf8_fma(acc, sr, dn);  // self term: dis[n]*h1[n]
        if ((t & 7) == 0) dis_l[nl] = dn;
        float4 b0v = *(const float4*)(b + fq);
        float4 b1v = *(const float4*)(b + fq + 4);
        float bb[8] = {b0v.x, b0v.y, b0v.z, b0v.w, b1v.x, b1v.y, b1v.z, b1v.w};
        float o[8];
#pragma unroll
        for (int i = 0; i < 8; ++i) o[i] = fmaxf(dn * acc[i] + bb[i], 0.0f);
        *(float4*)(zr)     = make_float4(o[0], o[1], o[2], o[3]);
        *(float4*)(zr + 4) = make_float4(o[4], o[5], o[6], o[7]);
    } else {
        // tail rows (only last half-block): zero so gemm reads are defined
        *(float4*)(zr)     = make_float4(0.f, 0.f, 0.f, 0.f);
        *(float4*)(zr + 4) = make_float4(0.f, 0.f, 0.f, 0.f);
    }
    __syncthreads();

    // Phase C: gemm 32x32, thread = 1 col x 4 rows (r2-proven)
    const int cc = t & 31;
    const int rbse = (t >> 5) * 4;
    float oacc[4] = {0.f, 0.f, 0.f, 0.f};
    for (int k0 = 0; k0 < 64; k0 += 4) {
        float w0 = ws[k0][cc], w1 = ws[k0 + 1][cc];
        float w2 = ws[k0 + 2][cc], w3 = ws[k0 + 3][cc];
#pragma unroll
        for (int i = 0; i < 4; ++i) {
            float4 xv = *(const float4*)&zs[(rbse + i) * 68 + k0];
            oacc[i] += xv.x * w0;
            oacc[i] += xv.y * w1;
            oacc[i] += xv.z * w2;
            oacc[i] += xv.w * w3;
        }
    }
#pragma unroll
    for (int i = 0; i < 4; ++i) {
        const int row = cb * 64 + hbase + rbse + i;
        if (row < N)
            ((unsigned short*)h2s)[(size_t)row * 32 + cc] =
                __bfloat16_as_ushort(
                    __float2bfloat16(oacc[i] * dis_l[rbse + i]));
    }
}

// ---- layer-2 agg: self-binned, 256 thr, 4 lanes/node x 64 (r11-proven).
// h2s pre-scaled by dis; pure accumulation; dn from local cur. ----
__global__ void __launch_bounds__(256) agg2_fb(
    const __hip_bfloat16* __restrict__ h2s, const unsigned* __restrict__ rec,
    const int* __restrict__ cursor, const float* __restrict__ b,
    float* __restrict__ out) {
    __shared__ unsigned lists[64 * 64];  // 16 KB
    __shared__ int cur[64];
    const int t = threadIdx.x;
    const int cb = blockIdx.x;
    if (t < 64) cur[t] = 0;
    __syncthreads();
    int m = cursor[cb];
    if (m > CAP) m = CAP;
    const unsigned* rb_ = rec + (size_t)cb * CAP;
    for (int i = t; i < m; i += 256) {
        unsigned u = rb_[i];
        int dl = (int)(u & 63u);
        int r = atomicAdd(&cur[dl], 1);
        if (r < 64) lists[dl * 64 + r] = u >> 6;
    }
    __syncthreads();

    const unsigned short* hp = (const unsigned short*)h2s;
    const int row0 = cb * 64;
    const int nl = t >> 2;
    const int n = row0 + nl;
    const int fq = (t & 3) * 8;
    const int c = cur[nl];
    const int deg = (c < 64) ? c : 64;
    const unsigned* lp = &lists[nl * 64];
    float acc[8];
#pragma unroll
    for (int i = 0; i < 8; ++i) acc[i] = 0.0f;
    int j = 0;
    for (; j + 2 <= deg; j += 2) {
        unsigned s0 = lp[j], s1 = lp[j + 1];
        uint4 r0 = *(const uint4*)(hp + (size_t)s0 * 32 + fq);
        uint4 r1 = *(const uint4*)(hp + (size_t)s1 * 32 + fq);
        bf8_acc(acc, r0);
        bf8_acc(acc, r1);
    }
    if (j < deg) {
        unsigned s0 = lp[j];
        uint4 r0 = *(const uint4*)(hp + (size_t)s0 * 32 + fq);
        bf8_acc(acc, r0);
    }
    if (n >= N) return;
    uint4 sr = *(const uint4*)(hp + (size_t)n * 32 + fq);
    bf8_acc(acc, sr);  // self term (h2s already has one dis factor)
    const float dn = rsqrtf((float)c + 1.0f);
    float4 b0 = *(const float4*)(b + fq);
    float4 b1 = *(const float4*)(b + fq + 4);
    *(float4*)(out + (size_t)n * 32 + fq) =
        make_float4(dn * acc[0] + b0.x, dn * acc[1] + b0.y,
                    dn * acc[2] + b0.z, dn * acc[3] + b0.w);
    *(float4*)(out + (size_t)n * 32 + fq + 4) =
        make_float4(dn * acc[4] + b1.x, dn * acc[5] + b1.y,
                    dn * acc[6] + b1.z, dn * acc[7] + b1.w);
}

extern "C" void kernel_launch(void* const* d_in, const int* in_sizes, int n_in,
                              void* d_out, int out_size, void* d_ws, size_t ws_size,
                              hipStream_t stream) {
    const float* x  = (const float*)d_in[0];
    const int*   ei = (const int*)d_in[1];
    const float* W1 = (const float*)d_in[2];
    const float* b1 = (const float*)d_in[3];
    const float* W2 = (const float*)d_in[4];
    const float* b2 = (const float*)d_in[5];
    float* out = (float*)d_out;

    const int* src = ei;
    const int* dst = ei + E;

    constexpr size_t NP = 100352;
    int*      cursor = (int*)d_ws;                             // 2048 ints
    float*    dis    = (float*)(cursor + 2048);                // NP floats
    unsigned* rec    = (unsigned*)(dis + NP);                  // NBINS*CAP u32 (9.6 MB)
    __hip_bfloat16* h1u = (__hip_bfloat16*)(rec + (size_t)NBINS * CAP); // N*64
    __hip_bfloat16* h2s = h1u + (size_t)N * 64;                          // N*32

    hipMemsetAsync(cursor, 0, 2048 * sizeof(int), stream);
    fused_pass1_gemm1<<<P1B + GB, 256, 0, stream>>>(x, W1, h1u, src, dst,
                                                    cursor, rec);
    degree_kernel<<<NBINS, 256, 0, stream>>>(rec, cursor, dis);
    agg1_gemm2_half<<<2 * NBINS, 256, 0, stream>>>(h1u, rec, cursor, dis, b1,
                                                   W2, h2s);
    agg2_fb<<<NBINS, 256, 0, stream>>>(h2s, rec, cursor, b2, out);
}

// Round 13
// 211.525 us; speedup vs baseline: 1.2893x; 1.2893x over previous
//
#include <hip/hip_runtime.h>
#include <hip/hip_bf16.h>

// GCN 2-layer, N=100000, E=1.6M, 64->64(relu)->32.
// out[d] = dis[d]*(sum_{s in N(d)} dis[s]*h[s] + dis[d]*h[d]) + b  (per layer).
// Pipeline (4 kernels + memset), NO pedge, NO z1 round trip:
//  pass1+gemm1: partition edges into 1563 dst-range buckets (64 dsts each,
//    rec = (src<<6)|(dst&63)); x@W1 -> h1u bf16 (single rounding).
//  degree_kernel: one block per bucket re-scans rec, LDS-histograms the
//    6-bit dst, writes dis[] = rsqrt(deg+1).
//  agg1_gemm2_reg: one 512-thr block per bucket. Self-bins rec into LDS
//    lists; 8 lanes/node weighted gathers (w = dis[s]); z = relu(...) stays
//    in REGISTERS (f32); per-node 64x32 matvec via p[32] partials from
//    LDS W2 (stride-33 pad) + 3-level shfl_xor reduce -> h2s bf16 * dis[n].
//    NO LDS z-tile / gemm phase: r8+r12 showed that form compiles to
//    VGPR~140 -> occupancy 10% -> 140us. __launch_bounds__(512,4) caps 128.
//  agg2_fb: self-binned, 4 lanes/node x 64, dn local, writes out f32.
// Locked-in lessons: r7 no per-edge LDS f32 atomics; r8/r12 no LDS-tile gemm
// fused into gather blocks (VGPR cliff); r9 no scattered global atomics;
// r3-r6 gather FETCH ~85-97MB is compulsory (8 XCDs pull the table) ~2.3TB/s.

constexpr int N = 100000;
constexpr int E = 1600000;
constexpr int NBINS = 1563;    // ceil(N/64) dst-ranges of 64
constexpr int HB    = 1568;    // padded bin count for pass1 LDS scratch
constexpr int CAP   = 1536;    // records per range (mean 1023, +16 sigma)
constexpr int P1B   = 391;     // pass1 blocks (4096 edges each)
constexpr int GB    = 1563;    // gemm1 blocks (64 rows each)

// ---- fused: pass1 partition (bid<P1B) | gemm1 outer-product (else) ----
__global__ void __launch_bounds__(256) fused_pass1_gemm1(
    const float* __restrict__ x, const float* __restrict__ W1,
    __hip_bfloat16* __restrict__ h1u,
    const int* __restrict__ src, const int* __restrict__ dst,
    int* __restrict__ cursor, unsigned* __restrict__ rec) {
    __shared__ float ws[64][64];    // 16 KB (pass1 reuses ws+xsT as scratch)
    __shared__ float xsT[64][64];   // 16 KB
    const int bid = blockIdx.x;
    const int t = threadIdx.x;
    if (bid < P1B) {
        int* hist  = (int*)ws;          // HB ints (spills into xsT: both
        int* rbase = hist + HB;         // arrays unused by pass1 blocks)
        int* rcur  = rbase + HB;
        for (int i = t; i < HB; i += 256) hist[i] = 0;
        __syncthreads();
        int myd[16], mys[16];
        const int e0 = bid * 4096;
#pragma unroll
        for (int it = 0; it < 16; ++it) {
            int idx = e0 + it * 256 + t;
            bool ok = idx < E;
            myd[it] = ok ? dst[idx] : -1;
            mys[it] = ok ? src[idx] : 0;
            if (ok) atomicAdd(&hist[myd[it] >> 6], 1);
        }
        __syncthreads();
        for (int i = t; i < HB; i += 256) {
            int h = hist[i];
            rbase[i] = (h > 0) ? atomicAdd(&cursor[i], h) : 0;
            rcur[i] = 0;
        }
        __syncthreads();
#pragma unroll
        for (int it = 0; it < 16; ++it) {
            if (myd[it] >= 0) {
                int cb = myd[it] >> 6;
                int r = atomicAdd(&rcur[cb], 1);
                int pos = rbase[cb] + r;
                if (pos < CAP)
                    rec[(size_t)cb * CAP + pos] =
                        ((unsigned)mys[it] << 6) | ((unsigned)myd[it] & 63u);
            }
        }
    } else {
        // ---- gemm block: 64 rows, outer-product 4x4 per thread ----
        const int row0 = (bid - P1B) * 64;
        for (int i = t * 4; i < 64 * 64; i += 1024) {
            float4 v = *(const float4*)(W1 + i);
            ws[i >> 6][i & 63]       = v.x;
            ws[i >> 6][(i & 63) + 1] = v.y;
            ws[i >> 6][(i & 63) + 2] = v.z;
            ws[i >> 6][(i & 63) + 3] = v.w;
        }
        {
            const int r  = t & 63;
            const int k0 = (t >> 6) * 16;
            const int gr = row0 + r;
            if (gr < N) {
#pragma unroll
                for (int kk = 0; kk < 16; kk += 4) {
                    float4 v = *(const float4*)(x + (size_t)gr * 64 + k0 + kk);
                    xsT[k0 + kk][r]     = v.x;
                    xsT[k0 + kk + 1][r] = v.y;
                    xsT[k0 + kk + 2][r] = v.z;
                    xsT[k0 + kk + 3][r] = v.w;
                }
            } else {
#pragma unroll
                for (int kk = 0; kk < 16; ++kk) xsT[k0 + kk][r] = 0.0f;
            }
        }
        __syncthreads();
        const int c4 = (t & 15) * 4;
        const int r4 = (t >> 4) * 4;
        float acc[4][4];
#pragma unroll
        for (int i = 0; i < 4; ++i)
#pragma unroll
            for (int j = 0; j < 4; ++j) acc[i][j] = 0.0f;
#pragma unroll 4
        for (int k = 0; k < 64; ++k) {
            float4 wv = *(const float4*)&ws[k][c4];
            float4 xv = *(const float4*)&xsT[k][r4];
            float xa[4] = {xv.x, xv.y, xv.z, xv.w};
            float wa[4] = {wv.x, wv.y, wv.z, wv.w};
#pragma unroll
            for (int i = 0; i < 4; ++i)
#pragma unroll
                for (int j = 0; j < 4; ++j) acc[i][j] += xa[i] * wa[j];
        }
#pragma unroll
        for (int i = 0; i < 4; ++i) {
            const int gr = row0 + r4 + i;
            if (gr < N) {
                unsigned short o[4];
#pragma unroll
                for (int j = 0; j < 4; ++j)
                    o[j] = __bfloat16_as_ushort(__float2bfloat16(acc[i][j]));
                *(ushort4*)((unsigned short*)h1u + (size_t)gr * 64 + c4) =
                    *(const ushort4*)o;
            }
        }
    }
}

// ---- degree: one block per bucket; histogram 6-bit dst -> dis[] ----
__global__ void __launch_bounds__(256) degree_kernel(
    const unsigned* __restrict__ rec, const int* __restrict__ cursor,
    float* __restrict__ dis) {
    __shared__ int cur[64];
    const int t = threadIdx.x;
    const int cb = blockIdx.x;
    if (t < 64) cur[t] = 0;
    __syncthreads();
    int m = cursor[cb];
    if (m > CAP) m = CAP;
    const unsigned* rb_ = rec + (size_t)cb * CAP;
    for (int i = t; i < m; i += 256)
        atomicAdd(&cur[rb_[i] & 63u], 1);
    __syncthreads();
    if (t < 64) {
        const int n = cb * 64 + t;
        if (n < N) dis[n] = rsqrtf((float)cur[t] + 1.0f);
    }
}

__device__ __forceinline__ void bf8_fma(float* acc, uint4 r, float w) {
    const unsigned u[4] = {r.x, r.y, r.z, r.w};
#pragma unroll
    for (int k = 0; k < 4; ++k) {
        acc[2 * k]     += __uint_as_float(u[k] << 16) * w;
        acc[2 * k + 1] += __uint_as_float(u[k] & 0xffff0000u) * w;
    }
}

__device__ __forceinline__ void bf8_acc(float* acc, uint4 r) {
    const unsigned u[4] = {r.x, r.y, r.z, r.w};
#pragma unroll
    for (int k = 0; k < 4; ++k) {
        acc[2 * k]     += __uint_as_float(u[k] << 16);
        acc[2 * k + 1] += __uint_as_float(u[k] & 0xffff0000u);
    }
}

// ---- fused layer-1 agg + register-resident gemm2: 512 thr / 64-dst bucket.
// Phase A: bin rec -> LDS lists. Phase B: 8 lanes/node weighted gathers,
// z = relu(dn*(acc + dn*h1[n]) + b) in REGISTERS. Phase C: per-node matvec
// z@W2 via p[32] partials over the lane's 8 k-values (W2 in LDS, stride 33:
// 2-way bank aliasing only) + shfl_xor reduce over the 8-lane group;
// lane l stores 4 bf16 cols of h2s[n] * dn. No LDS z-tile, no 2nd barrier.
__global__ void __launch_bounds__(512, 4) agg1_gemm2_reg(
    const __hip_bfloat16* __restrict__ h1u, const unsigned* __restrict__ rec,
    const int* __restrict__ cursor, const float* __restrict__ dis,
    const float* __restrict__ b, const float* __restrict__ W2,
    __hip_bfloat16* __restrict__ h2s) {
    __shared__ unsigned lists[64 * 64];  // 16 KB
    __shared__ float    ws[64][33];      // 8.4 KB W2, padded stride
    __shared__ int      cur[64];
    const int t = threadIdx.x;
    const int cb = blockIdx.x;
    for (int i = t; i < 2048; i += 512) ws[i >> 5][i & 31] = W2[i];
    if (t < 64) cur[t] = 0;
    __syncthreads();
    int m = cursor[cb];
    if (m > CAP) m = CAP;
    const unsigned* rb_ = rec + (size_t)cb * CAP;
    for (int i = t; i < m; i += 512) {
        unsigned u = rb_[i];
        int dl = (int)(u & 63u);
        int r = atomicAdd(&cur[dl], 1);
        if (r < 64) lists[dl * 64 + r] = u >> 6;
    }
    __syncthreads();

    const unsigned short* hp = (const unsigned short*)h1u;
    const int row0 = cb * 64;
    const int nl = t >> 3;
    const int n = row0 + nl;
    const int l = t & 7;
    const int fq = l * 8;
    const int c = cur[nl];
    const int deg = (c < 64) ? c : 64;
    const unsigned* lp = &lists[nl * 64];
    float acc[8];
#pragma unroll
    for (int i = 0; i < 8; ++i) acc[i] = 0.0f;
    int j = 0;
    for (; j + 2 <= deg; j += 2) {
        unsigned s0 = lp[j], s1 = lp[j + 1];
        float w0 = dis[s0], w1 = dis[s1];
        uint4 r0 = *(const uint4*)(hp + (size_t)s0 * 64 + fq);
        uint4 r1 = *(const uint4*)(hp + (size_t)s1 * 64 + fq);
        bf8_fma(acc, r0, w0);
        bf8_fma(acc, r1, w1);
    }
    if (j < deg) {
        unsigned s0 = lp[j];
        float w0 = dis[s0];
        uint4 r0 = *(const uint4*)(hp + (size_t)s0 * 64 + fq);
        bf8_fma(acc, r0, w0);
    }
    if (n >= N) return;   // uniform across the 8-lane group; no later barrier
    const float dn = rsqrtf((float)c + 1.0f);
    uint4 sr = *(const uint4*)(hp + (size_t)n * 64 + fq);
    bf8_fma(acc, sr, dn);  // self term: dis[n]*h1[n]
    float4 b0v = *(const float4*)(b + fq);
    float4 b1v = *(const float4*)(b + fq + 4);
    float bb[8] = {b0v.x, b0v.y, b0v.z, b0v.w, b1v.x, b1v.y, b1v.z, b1v.w};
#pragma unroll
    for (int i = 0; i < 8; ++i) acc[i] = fmaxf(dn * acc[i] + bb[i], 0.0f);

    // Phase C: p[c] = sum_k z[k]*W2[k][c]; this lane covers k in [fq, fq+8)
    float p[32];
#pragma unroll
    for (int cc = 0; cc < 32; ++cc) {
        float s = 0.0f;
#pragma unroll
        for (int i = 0; i < 8; ++i) s += acc[i] * ws[fq + i][cc];
        p[cc] = s;
    }
#pragma unroll
    for (int cc = 0; cc < 32; ++cc) {
        p[cc] += __shfl_xor(p[cc], 1);
        p[cc] += __shfl_xor(p[cc], 2);
        p[cc] += __shfl_xor(p[cc], 4);
    }
    // lane l writes columns [4l, 4l+4) of h2s[n] = (z@W2)*dis[n]
    unsigned short o[4];
#pragma unroll
    for (int i = 0; i < 4; ++i)
        o[i] = __bfloat16_as_ushort(__float2bfloat16(p[4 * l + i] * dn));
    *(ushort4*)((unsigned short*)h2s + (size_t)n * 32 + 4 * l) =
        *(const ushort4*)o;
}

// ---- layer-2 agg: self-binned, 256 thr, 4 lanes/node x 64 (r11-proven).
// h2s pre-scaled by dis; pure accumulation; dn from local cur. ----
__global__ void __launch_bounds__(256) agg2_fb(
    const __hip_bfloat16* __restrict__ h2s, const unsigned* __restrict__ rec,
    const int* __restrict__ cursor, const float* __restrict__ b,
    float* __restrict__ out) {
    __shared__ unsigned lists[64 * 64];  // 16 KB
    __shared__ int cur[64];
    const int t = threadIdx.x;
    const int cb = blockIdx.x;
    if (t < 64) cur[t] = 0;
    __syncthreads();
    int m = cursor[cb];
    if (m > CAP) m = CAP;
    const unsigned* rb_ = rec + (size_t)cb * CAP;
    for (int i = t; i < m; i += 256) {
        unsigned u = rb_[i];
        int dl = (int)(u & 63u);
        int r = atomicAdd(&cur[dl], 1);
        if (r < 64) lists[dl * 64 + r] = u >> 6;
    }
    __syncthreads();

    const unsigned short* hp = (const unsigned short*)h2s;
    const int row0 = cb * 64;
    const int nl = t >> 2;
    const int n = row0 + nl;
    const int fq = (t & 3) * 8;
    const int c = cur[nl];
    const int deg = (c < 64) ? c : 64;
    const unsigned* lp = &lists[nl * 64];
    float acc[8];
#pragma unroll
    for (int i = 0; i < 8; ++i) acc[i] = 0.0f;
    int j = 0;
    for (; j + 2 <= deg; j += 2) {
        unsigned s0 = lp[j], s1 = lp[j + 1];
        uint4 r0 = *(const uint4*)(hp + (size_t)s0 * 32 + fq);
        uint4 r1 = *(const uint4*)(hp + (size_t)s1 * 32 + fq);
        bf8_acc(acc, r0);
        bf8_acc(acc, r1);
    }
    if (j < deg) {
        unsigned s0 = lp[j];
        uint4 r0 = *(const uint4*)(hp + (size_t)s0 * 32 + fq);
        bf8_acc(acc, r0);
    }
    if (n >= N) return;
    uint4 sr = *(const uint4*)(hp + (size_t)n * 32 + fq);
    bf8_acc(acc, sr);  // self term (h2s already has one dis factor)
    const float dn = rsqrtf((float)c + 1.0f);
    float4 b0 = *(const float4*)(b + fq);
    float4 b1 = *(const float4*)(b + fq + 4);
    *(float4*)(out + (size_t)n * 32 + fq) =
        make_float4(dn * acc[0] + b0.x, dn * acc[1] + b0.y,
                    dn * acc[2] + b0.z, dn * acc[3] + b0.w);
    *(float4*)(out + (size_t)n * 32 + fq + 4) =
        make_float4(dn * acc[4] + b1.x, dn * acc[5] + b1.y,
                    dn * acc[6] + b1.z, dn * acc[7] + b1.w);
}

extern "C" void kernel_launch(void* const* d_in, const int* in_sizes, int n_in,
                              void* d_out, int out_size, void* d_ws, size_t ws_size,
                              hipStream_t stream) {
    const float* x  = (const float*)d_in[0];
    const int*   ei = (const int*)d_in[1];
    const float* W1 = (const float*)d_in[2];
    const float* b1 = (const float*)d_in[3];
    const float* W2 = (const float*)d_in[4];
    const float* b2 = (const float*)d_in[5];
    float* out = (float*)d_out;

    const int* src = ei;
    const int* dst = ei + E;

    constexpr size_t NP = 100352;
    int*      cursor = (int*)d_ws;                             // 2048 ints
    float*    dis    = (float*)(cursor + 2048);                // NP floats
    unsigned* rec    = (unsigned*)(dis + NP);                  // NBINS*CAP u32 (9.6 MB)
    __hip_bfloat16* h1u = (__hip_bfloat16*)(rec + (size_t)NBINS * CAP); // N*64
    __hip_bfloat16* h2s = h1u + (size_t)N * 64;                          // N*32

    hipMemsetAsync(cursor, 0, 2048 * sizeof(int), stream);
    fused_pass1_gemm1<<<P1B + GB, 256, 0, stream>>>(x, W1, h1u, src, dst,
                                                    cursor, rec);
    degree_kernel<<<NBINS, 256, 0, stream>>>(rec, cursor, dis);
    agg1_gemm2_reg<<<NBINS, 512, 0, stream>>>(h1u, rec, cursor, dis, b1, W2,
                                              h2s);
    agg2_fb<<<NBINS, 256, 0, stream>>>(h2s, rec, cursor, b2, out);
}

// Round 15
// 190.863 us; speedup vs baseline: 1.4288x; 1.1083x over previous
//
#include <hip/hip_runtime.h>
#include <hip/hip_bf16.h>

// GCN 2-layer, N=100000, E=1.6M, 64->64(relu)->32.
// out[d] = dis[d]*(sum_{s in N(d)} dis[s]*h[s] + dis[d]*h[d]) + b  (per layer).
// Pipeline (4 kernels + memset), NO pedge, NO z1 round trip:
//  pass1+gemm1: partition edges into 1563 dst-range buckets (64 dsts each,
//    rec = (src<<6)|(dst&63)); x@W1 -> h1u bf16 (single rounding).
//  degree_kernel: one block per bucket re-scans rec, LDS-histograms the
//    6-bit dst, writes dis[] = rsqrt(deg+1).
//  agg1_gemm2_reg: one 512-thr block per bucket. Self-bins rec into LDS
//    lists; 8 lanes/node weighted gathers (w = dis[s]); z = relu(...) in
//    REGISTERS; per-node 64x32 matvec via p[32] partials from LDS W2
//    (stride-33) + 3-step shfl_xor REDUCE-SCATTER (compile-time p indices;
//    r13 lesson: p[4*l+i] runtime index demoted p to scratch -> 123MB
//    write traffic). Lane l ends holding 4 fully-summed columns at
//    colbase = bit-reversed(l) -> h2s bf16 * dis[n].
//  agg2_fb: self-binned, 4 lanes/node x 64, dn local, writes out f32.
// Locked-in lessons: r7 no per-edge LDS f32 atomics; r8/r12 no LDS-tile gemm
// in gather blocks (VGPR cliff); r9 no scattered global atomics; r13 no
// runtime-indexed register arrays; r3-r6 gather FETCH ~85-97MB compulsory.

constexpr int N = 100000;
constexpr int E = 1600000;
constexpr int NBINS = 1563;    // ceil(N/64) dst-ranges of 64
constexpr int HB    = 1568;    // padded bin count for pass1 LDS scratch
constexpr int CAP   = 1536;    // records per range (mean 1023, +16 sigma)
constexpr int P1B   = 391;     // pass1 blocks (4096 edges each)
constexpr int GB    = 1563;    // gemm1 blocks (64 rows each)

// ---- fused: pass1 partition (bid<P1B) | gemm1 outer-product (else) ----
__global__ void __launch_bounds__(256) fused_pass1_gemm1(
    const float* __restrict__ x, const float* __restrict__ W1,
    __hip_bfloat16* __restrict__ h1u,
    const int* __restrict__ src, const int* __restrict__ dst,
    int* __restrict__ cursor, unsigned* __restrict__ rec) {
    __shared__ float ws[64][64];    // 16 KB (pass1 reuses ws+xsT as scratch)
    __shared__ float xsT[64][64];   // 16 KB
    const int bid = blockIdx.x;
    const int t = threadIdx.x;
    if (bid < P1B) {
        int* hist  = (int*)ws;          // HB ints (spills into xsT: both
        int* rbase = hist + HB;         // arrays unused by pass1 blocks)
        int* rcur  = rbase + HB;
        for (int i = t; i < HB; i += 256) hist[i] = 0;
        __syncthreads();
        int myd[16], mys[16];
        const int e0 = bid * 4096;
#pragma unroll
        for (int it = 0; it < 16; ++it) {
            int idx = e0 + it * 256 + t;
            bool ok = idx < E;
            myd[it] = ok ? dst[idx] : -1;
            mys[it] = ok ? src[idx] : 0;
            if (ok) atomicAdd(&hist[myd[it] >> 6], 1);
        }
        __syncthreads();
        for (int i = t; i < HB; i += 256) {
            int h = hist[i];
            rbase[i] = (h > 0) ? atomicAdd(&cursor[i], h) : 0;
            rcur[i] = 0;
        }
        __syncthreads();
#pragma unroll
        for (int it = 0; it < 16; ++it) {
            if (myd[it] >= 0) {
                int cb = myd[it] >> 6;
                int r = atomicAdd(&rcur[cb], 1);
                int pos = rbase[cb] + r;
                if (pos < CAP)
                    rec[(size_t)cb * CAP + pos] =
                        ((unsigned)mys[it] << 6) | ((unsigned)myd[it] & 63u);
            }
        }
    } else {
        // ---- gemm block: 64 rows, outer-product 4x4 per thread ----
        const int row0 = (bid - P1B) * 64;
        for (int i = t * 4; i < 64 * 64; i += 1024) {
            float4 v = *(const float4*)(W1 + i);
            ws[i >> 6][i & 63]       = v.x;
            ws[i >> 6][(i & 63) + 1] = v.y;
            ws[i >> 6][(i & 63) + 2] = v.z;
            ws[i >> 6][(i & 63) + 3] = v.w;
        }
        {
            const int r  = t & 63;
            const int k0 = (t >> 6) * 16;
            const int gr = row0 + r;
            if (gr < N) {
#pragma unroll
                for (int kk = 0; kk < 16; kk += 4) {
                    float4 v = *(const float4*)(x + (size_t)gr * 64 + k0 + kk);
                    xsT[k0 + kk][r]     = v.x;
                    xsT[k0 + kk + 1][r] = v.y;
                    xsT[k0 + kk + 2][r] = v.z;
                    xsT[k0 + kk + 3][r] = v.w;
                }
            } else {
#pragma unroll
                for (int kk = 0; kk < 16; ++kk) xsT[k0 + kk][r] = 0.0f;
            }
        }
        __syncthreads();
        const int c4 = (t & 15) * 4;
        const int r4 = (t >> 4) * 4;
        float acc[4][4];
#pragma unroll
        for (int i = 0; i < 4; ++i)
#pragma unroll
            for (int j = 0; j < 4; ++j) acc[i][j] = 0.0f;
#pragma unroll 4
        for (int k = 0; k < 64; ++k) {
            float4 wv = *(const float4*)&ws[k][c4];
            float4 xv = *(const float4*)&xsT[k][r4];
            float xa[4] = {xv.x, xv.y, xv.z, xv.w};
            float wa[4] = {wv.x, wv.y, wv.z, wv.w};
#pragma unroll
            for (int i = 0; i < 4; ++i)
#pragma unroll
                for (int j = 0; j < 4; ++j) acc[i][j] += xa[i] * wa[j];
        }
#pragma unroll
        for (int i = 0; i < 4; ++i) {
            const int gr = row0 + r4 + i;
            if (gr < N) {
                unsigned short o[4];
#pragma unroll
                for (int j = 0; j < 4; ++j)
                    o[j] = __bfloat16_as_ushort(__float2bfloat16(acc[i][j]));
                *(ushort4*)((unsigned short*)h1u + (size_t)gr * 64 + c4) =
                    *(const ushort4*)o;
            }
        }
    }
}

// ---- degree: one block per bucket; histogram 6-bit dst -> dis[] ----
__global__ void __launch_bounds__(256) degree_kernel(
    const unsigned* __restrict__ rec, const int* __restrict__ cursor,
    float* __restrict__ dis) {
    __shared__ int cur[64];
    const int t = threadIdx.x;
    const int cb = blockIdx.x;
    if (t < 64) cur[t] = 0;
    __syncthreads();
    int m = cursor[cb];
    if (m > CAP) m = CAP;
    const unsigned* rb_ = rec + (size_t)cb * CAP;
    for (int i = t; i < m; i += 256)
        atomicAdd(&cur[rb_[i] & 63u], 1);
    __syncthreads();
    if (t < 64) {
        const int n = cb * 64 + t;
        if (n < N) dis[n] = rsqrtf((float)cur[t] + 1.0f);
    }
}

__device__ __forceinline__ void bf8_fma(float* acc, uint4 r, float w) {
    const unsigned u[4] = {r.x, r.y, r.z, r.w};
#pragma unroll
    for (int k = 0; k < 4; ++k) {
        acc[2 * k]     += __uint_as_float(u[k] << 16) * w;
        acc[2 * k + 1] += __uint_as_float(u[k] & 0xffff0000u) * w;
    }
}

__device__ __forceinline__ void bf8_acc(float* acc, uint4 r) {
    const unsigned u[4] = {r.x, r.y, r.z, r.w};
#pragma unroll
    for (int k = 0; k < 4; ++k) {
        acc[2 * k]     += __uint_as_float(u[k] << 16);
        acc[2 * k + 1] += __uint_as_float(u[k] & 0xffff0000u);
    }
}

// ---- fused layer-1 agg + register-resident gemm2: 512 thr / 64-dst bucket.
// Phase A: bin rec -> LDS lists. Phase B: 8 lanes/node weighted gathers,
// z in REGISTERS. Phase C: p[32] partials from LDS W2, then 3-step shfl_xor
// reduce-scatter (all p indices compile-time); lane l ends with 4 summed
// columns at colbase = (l&1)*16 + ((l>>1)&1)*8 + ((l>>2)&1)*4. ----
__global__ void __launch_bounds__(512, 2) agg1_gemm2_reg(
    const __hip_bfloat16* __restrict__ h1u, const unsigned* __restrict__ rec,
    const int* __restrict__ cursor, const float* __restrict__ dis,
    const float* __restrict__ b, const float* __restrict__ W2,
    __hip_bfloat16* __restrict__ h2s) {
    __shared__ unsigned lists[64 * 64];  // 16 KB
    __shared__ float    ws[64][33];      // 8.4 KB W2, padded stride
    __shared__ int      cur[64];
    const int t = threadIdx.x;
    const int cb = blockIdx.x;
    for (int i = t; i < 2048; i += 512) ws[i >> 5][i & 31] = W2[i];
    if (t < 64) cur[t] = 0;
    __syncthreads();
    int m = cursor[cb];
    if (m > CAP) m = CAP;
    const unsigned* rb_ = rec + (size_t)cb * CAP;
    for (int i = t; i < m; i += 512) {
        unsigned u = rb_[i];
        int dl = (int)(u & 63u);
        int r = atomicAdd(&cur[dl], 1);
        if (r < 64) lists[dl * 64 + r] = u >> 6;
    }
    __syncthreads();

    const unsigned short* hp = (const unsigned short*)h1u;
    const int row0 = cb * 64;
    const int nl = t >> 3;
    const int n = row0 + nl;
    const int l = t & 7;
    const int fq = l * 8;
    const int c = cur[nl];
    const int deg = (c < 64) ? c : 64;
    const unsigned* lp = &lists[nl * 64];
    float acc[8];
#pragma unroll
    for (int i = 0; i < 8; ++i) acc[i] = 0.0f;
    int j = 0;
    for (; j + 2 <= deg; j += 2) {
        unsigned s0 = lp[j], s1 = lp[j + 1];
        float w0 = dis[s0], w1 = dis[s1];
        uint4 r0 = *(const uint4*)(hp + (size_t)s0 * 64 + fq);
        uint4 r1 = *(const uint4*)(hp + (size_t)s1 * 64 + fq);
        bf8_fma(acc, r0, w0);
        bf8_fma(acc, r1, w1);
    }
    if (j < deg) {
        unsigned s0 = lp[j];
        float w0 = dis[s0];
        uint4 r0 = *(const uint4*)(hp + (size_t)s0 * 64 + fq);
        bf8_fma(acc, r0, w0);
    }
    if (n >= N) return;   // uniform across the 8-lane group; no later barrier
    const float dn = rsqrtf((float)c + 1.0f);
    uint4 sr = *(const uint4*)(hp + (size_t)n * 64 + fq);
    bf8_fma(acc, sr, dn);  // self term: dis[n]*h1[n]
    float4 b0v = *(const float4*)(b + fq);
    float4 b1v = *(const float4*)(b + fq + 4);
    float bb[8] = {b0v.x, b0v.y, b0v.z, b0v.w, b1v.x, b1v.y, b1v.z, b1v.w};
#pragma unroll
    for (int i = 0; i < 8; ++i) acc[i] = fmaxf(dn * acc[i] + bb[i], 0.0f);

    // Phase C1: p[cc] = sum over this lane's k in [fq, fq+8) of z[k]*W2[k][cc]
    float p[32];
#pragma unroll
    for (int cc = 0; cc < 32; ++cc) {
        float s = 0.0f;
#pragma unroll
        for (int i = 0; i < 8; ++i) s += acc[i] * ws[fq + i][cc];
        p[cc] = s;
    }
    // Phase C2: reduce-scatter over the 8-lane group (compile-time indices).
    const bool hi1 = (l & 1) != 0;
#pragma unroll
    for (int cc = 0; cc < 16; ++cc) {
        float send = hi1 ? p[cc] : p[cc + 16];
        float keep = hi1 ? p[cc + 16] : p[cc];
        p[cc] = keep + __shfl_xor(send, 1);
    }
    const bool hi2 = (l & 2) != 0;
#pragma unroll
    for (int cc = 0; cc < 8; ++cc) {
        float send = hi2 ? p[cc] : p[cc + 8];
        float keep = hi2 ? p[cc + 8] : p[cc];
        p[cc] = keep + __shfl_xor(send, 2);
    }
    const bool hi3 = (l & 4) != 0;
#pragma unroll
    for (int cc = 0; cc < 4; ++cc) {
        float send = hi3 ? p[cc] : p[cc + 4];
        float keep = hi3 ? p[cc + 4] : p[cc];
        p[cc] = keep + __shfl_xor(send, 4);
    }
    // lane l holds summed columns [colbase, colbase+4)
    const int colbase = (l & 1) * 16 + ((l >> 1) & 1) * 8 + ((l >> 2) & 1) * 4;
    unsigned short o[4];
#pragma unroll
    for (int i = 0; i < 4; ++i)
        o[i] = __bfloat16_as_ushort(__float2bfloat16(p[i] * dn));
    *(ushort4*)((unsigned short*)h2s + (size_t)n * 32 + colbase) =
        *(const ushort4*)o;
}

// ---- layer-2 agg: self-binned, 256 thr, 4 lanes/node x 64 (r11-proven).
// h2s pre-scaled by dis; pure accumulation; dn from local cur. ----
__global__ void __launch_bounds__(256) agg2_fb(
    const __hip_bfloat16* __restrict__ h2s, const unsigned* __restrict__ rec,
    const int* __restrict__ cursor, const float* __restrict__ b,
    float* __restrict__ out) {
    __shared__ unsigned lists[64 * 64];  // 16 KB
    __shared__ int cur[64];
    const int t = threadIdx.x;
    const int cb = blockIdx.x;
    if (t < 64) cur[t] = 0;
    __syncthreads();
    int m = cursor[cb];
    if (m > CAP) m = CAP;
    const unsigned* rb_ = rec + (size_t)cb * CAP;
    for (int i = t; i < m; i += 256) {
        unsigned u = rb_[i];
        int dl = (int)(u & 63u);
        int r = atomicAdd(&cur[dl], 1);
        if (r < 64) lists[dl * 64 + r] = u >> 6;
    }
    __syncthreads();

    const unsigned short* hp = (const unsigned short*)h2s;
    const int row0 = cb * 64;
    const int nl = t >> 2;
    const int n = row0 + nl;
    const int fq = (t & 3) * 8;
    const int c = cur[nl];
    const int deg = (c < 64) ? c : 64;
    const unsigned* lp = &lists[nl * 64];
    float acc[8];
#pragma unroll
    for (int i = 0; i < 8; ++i) acc[i] = 0.0f;
    int j = 0;
    for (; j + 2 <= deg; j += 2) {
        unsigned s0 = lp[j], s1 = lp[j + 1];
        uint4 r0 = *(const uint4*)(hp + (size_t)s0 * 32 + fq);
        uint4 r1 = *(const uint4*)(hp + (size_t)s1 * 32 + fq);
        bf8_acc(acc, r0);
        bf8_acc(acc, r1);
    }
    if (j < deg) {
        unsigned s0 = lp[j];
        uint4 r0 = *(const uint4*)(hp + (size_t)s0 * 32 + fq);
        bf8_acc(acc, r0);
    }
    if (n >= N) return;
    uint4 sr = *(const uint4*)(hp + (size_t)n * 32 + fq);
    bf8_acc(acc, sr);  // self term (h2s already has one dis factor)
    const float dn = rsqrtf((float)c + 1.0f);
    float4 b0 = *(const float4*)(b + fq);
    float4 b1 = *(const float4*)(b + fq + 4);
    *(float4*)(out + (size_t)n * 32 + fq) =
        make_float4(dn * acc[0] + b0.x, dn * acc[1] + b0.y,
                    dn * acc[2] + b0.z, dn * acc[3] + b0.w);
    *(float4*)(out + (size_t)n * 32 + fq + 4) =
        make_float4(dn * acc[4] + b1.x, dn * acc[5] + b1.y,
                    dn * acc[6] + b1.z, dn * acc[7] + b1.w);
}

extern "C" void kernel_launch(void* const* d_in, const int* in_sizes, int n_in,
                              void* d_out, int out_size, void* d_ws, size_t ws_size,
                              hipStream_t stream) {
    const float* x  = (const float*)d_in[0];
    const int*   ei = (const int*)d_in[1];
    const float* W1 = (const float*)d_in[2];
    const float* b1 = (const float*)d_in[3];
    const float* W2 = (const float*)d_in[4];
    const float* b2 = (const float*)d_in[5];
    float* out = (float*)d_out;

    const int* src = ei;
    const int* dst = ei + E;

    constexpr size_t NP = 100352;
    int*      cursor = (int*)d_ws;                             // 2048 ints
    float*    dis    = (float*)(cursor + 2048);                // NP floats
    unsigned* rec    = (unsigned*)(dis + NP);                  // NBINS*CAP u32 (9.6 MB)
    __hip_bfloat16* h1u = (__hip_bfloat16*)(rec + (size_t)NBINS * CAP); // N*64
    __hip_bfloat16* h2s = h1u + (size_t)N * 64;                          // N*32

    hipMemsetAsync(cursor, 0, 2048 * sizeof(int), stream);
    fused_pass1_gemm1<<<P1B + GB, 256, 0, stream>>>(x, W1, h1u, src, dst,
                                                    cursor, rec);
    degree_kernel<<<NBINS, 256, 0, stream>>>(rec, cursor, dis);
    agg1_gemm2_reg<<<NBINS, 512, 0, stream>>>(h1u, rec, cursor, dis, b1, W2,
                                              h2s);
    agg2_fb<<<NBINS, 256, 0, stream>>>(h2s, rec, cursor, b2, out);
}